// Round 5
// baseline (717.541 us; speedup 1.0000x reference)
//
#include <hip/hip_runtime.h>

#define TSTEPS 512   // LSTM sequence length (2048/4)
#define HID    64

typedef float v2f __attribute__((ext_vector_type(2)));

__device__ __forceinline__ v2f pkfma(v2f a, v2f b, v2f c) {
#if __has_builtin(__builtin_elementwise_fma)
  return __builtin_elementwise_fma(a, b, c);
#else
  return (v2f){fmaf(a.x, b.x, c.x), fmaf(a.y, b.y, c.y)};
#endif
}

__device__ __forceinline__ float sigm(float x) {
  return 1.0f / (1.0f + __expf(-x));
}
__device__ __forceinline__ float tanh_(float x) {
  return 1.0f - 2.0f / (1.0f + __expf(2.0f * x));
}

// ---------------------------------------------------------------------------
// Kernel 1: conv1 (3->16, k=3, same) + maxpool2.  x:[256,2048,3] -> t1:[256,1024,16]
// ---------------------------------------------------------------------------
__global__ __launch_bounds__(256) void conv1_pool(
    const float* __restrict__ x, const float* __restrict__ w,
    const float* __restrict__ bias, float* __restrict__ out) {
  __shared__ float ws[144];
  __shared__ float bs[16];
  const int tid = threadIdx.x;
  if (tid < 144) ws[tid] = w[tid];
  if (tid < 16)  bs[tid] = bias[tid];
  __syncthreads();

  const int idx = blockIdx.x * 256 + tid;   // b*1024 + t2
  const int b  = idx >> 10;
  const int t2 = idx & 1023;
  const float* xb = x + (size_t)b * 2048 * 3;
  const int p0 = 2 * t2;

  float xv[4][3];
#pragma unroll
  for (int j = 0; j < 4; ++j) {
    const int p = p0 - 1 + j;
    const bool ok = (p >= 0) && (p < 2048);
#pragma unroll
    for (int c = 0; c < 3; ++c) xv[j][c] = ok ? xb[p * 3 + c] : 0.0f;
  }

  float4 o4[4];
  float* op = (float*)o4;
#pragma unroll
  for (int o = 0; o < 16; ++o) {
    float s0 = bs[o], s1 = bs[o];
#pragma unroll
    for (int c = 0; c < 3; ++c) {
#pragma unroll
      for (int k = 0; k < 3; ++k) {
        const float wv = ws[(o * 3 + c) * 3 + k];
        s0 = fmaf(xv[k][c],     wv, s0);
        s1 = fmaf(xv[k + 1][c], wv, s1);
      }
    }
    op[o] = fmaxf(s0, s1);
  }
  float4* dst = (float4*)(out + (size_t)idx * 16);
  dst[0] = o4[0]; dst[1] = o4[1]; dst[2] = o4[2]; dst[3] = o4[3];
}

// ---------------------------------------------------------------------------
// Kernel 2: conv2 (16->32, k=3, same) + maxpool2. t1:[256,1024,16] -> feat:[256,512,32]
// ---------------------------------------------------------------------------
__global__ __launch_bounds__(256) void conv2_pool(
    const float* __restrict__ t1, const float* __restrict__ w,
    const float* __restrict__ bias, float* __restrict__ out) {
  __shared__ float ws[1536];
  __shared__ float bs[32];
  const int tid = threadIdx.x;
  for (int i = tid; i < 1536; i += 256) ws[i] = w[i];
  if (tid < 32) bs[tid] = bias[tid];
  __syncthreads();

  const int idx = blockIdx.x * 256 + tid;   // b*512 + t2
  const int b  = idx >> 9;
  const int t2 = idx & 511;
  const float* tb = t1 + (size_t)b * 1024 * 16;
  const int p0 = 2 * t2;

  float4 r4[4][4];
  float* r = (float*)r4;
#pragma unroll
  for (int j = 0; j < 4; ++j) {
    const int p = p0 - 1 + j;
    if (p >= 0 && p < 1024) {
      const float4* s = (const float4*)(tb + p * 16);
      r4[j][0] = s[0]; r4[j][1] = s[1]; r4[j][2] = s[2]; r4[j][3] = s[3];
    } else {
      const float4 z = {0.f, 0.f, 0.f, 0.f};
      r4[j][0] = z; r4[j][1] = z; r4[j][2] = z; r4[j][3] = z;
    }
  }

  float4 o4[8];
  float* op = (float*)o4;
#pragma unroll 4
  for (int o = 0; o < 32; ++o) {
    float s0 = bs[o], s1 = bs[o];
    const float* wo = &ws[o * 48];
#pragma unroll
    for (int c = 0; c < 16; ++c) {
      const float w0 = wo[c * 3], w1 = wo[c * 3 + 1], w2 = wo[c * 3 + 2];
      s0 = fmaf(r[0 * 16 + c], w0, s0);
      s0 = fmaf(r[1 * 16 + c], w1, s0);
      s0 = fmaf(r[2 * 16 + c], w2, s0);
      s1 = fmaf(r[1 * 16 + c], w0, s1);
      s1 = fmaf(r[2 * 16 + c], w1, s1);
      s1 = fmaf(r[3 * 16 + c], w2, s1);
    }
    op[o] = fmaxf(s0, s1);
  }
  float4* dst = (float4*)(out + (size_t)idx * 32);
#pragma unroll
  for (int q = 0; q < 8; ++q) dst[q] = o4[q];
}

// ---------------------------------------------------------------------------
// Kernel 2.5: pack LSTM weights into a unified row layout so the lstm kernel's
// weight load is branch-free (SROA-promotable to VGPRs).
//   Wpack[r][0..127], biasv[r], r in [0,512):
//     r < 256 (layer0 row r):   [w_hh0_row(64) | w_ih0_row(32) | zeros(32)]
//     r >= 256 (layer1 row q):  [w_ih1_row(64) | w_hh1_row(64)]
// ---------------------------------------------------------------------------
__global__ __launch_bounds__(128) void pack_weights(
    const float* __restrict__ w_ih0, const float* __restrict__ w_hh0,
    const float* __restrict__ b_ih0, const float* __restrict__ b_hh0,
    const float* __restrict__ w_ih1, const float* __restrict__ w_hh1,
    const float* __restrict__ b_ih1, const float* __restrict__ b_hh1,
    float* __restrict__ Wpack, float* __restrict__ biasv) {
  const int r = blockIdx.x;    // 512 rows
  const int j = threadIdx.x;   // 128 cols
  float v;
  if (r < 256) {
    if (j < 64)      v = w_hh0[r * 64 + j];
    else if (j < 96) v = w_ih0[r * 32 + (j - 64)];
    else             v = 0.0f;
    if (j == 0) biasv[r] = b_ih0[r] + b_hh0[r];
  } else {
    const int q = r - 256;
    if (j < 64) v = w_ih1[q * 64 + j];
    else        v = w_hh1[q * 64 + (j - 64)];
    if (j == 0) biasv[r] = b_ih1[q] + b_hh1[q];
  }
  Wpack[r * 128 + j] = v;
}

// ---------------------------------------------------------------------------
// Kernel 3: fused 2-layer LSTM + fc.  One block per batch element, 8 waves
// (512 threads, exactly 2 waves/SIMD via amdgpu_waves_per_eu(2,2) so the
// allocator uses the full 256-VGPR budget and keeps the 128-float weight row
// register-resident).  Thread = one packed gate-row; waves 0-3 = layer0,
// waves 4-7 = layer1 (pipelined one step behind).
//
// Gate phase is IDENTICAL for every wave (no divergence):
//   pre[tid] = Wa(64)·h0 + Wb(64)·vB + bias
// where vB = own h1 (layer1 waves) or padded x_t (layer0 waves; pad weights
// are zero).  One barrier per step; update phase redundantly computed per
// wave with private c-state into its OWN hbuf slot (no second barrier).
// ---------------------------------------------------------------------------
__global__ __attribute__((amdgpu_flat_work_group_size(512, 512),
                          amdgpu_waves_per_eu(2, 2)))
void lstm_fused(
    const float* __restrict__ feat,
    const float* __restrict__ Wpack, const float* __restrict__ biasv,
    const float* __restrict__ fc_w, const float* __restrict__ fc_b,
    float* __restrict__ out) {
  __shared__ float4 featL[2056];      // 256 staged rows + 8 zero-pad float4
  __shared__ float  pre[2][512];      // double-buffered on t&1
  __shared__ float  hbuf[8][128];     // per-wave private: [0..63]=h0, [64..127]=h1

  const int tid = threadIdx.x;
  const int wv  = tid >> 6;           // wave id 0..7
  const int u   = tid & 63;           // lane / unit
  const int b   = blockIdx.x;
  const bool isL1 = (wv >= 4);

  // ---- branch-free weight row load -> registers ----
  v2f wa[32], wb[32];
  {
    const v2f* wrow = (const v2f*)(Wpack + (size_t)tid * 128);
#pragma unroll
    for (int k = 0; k < 32; ++k) wa[k] = wrow[k];
#pragma unroll
    for (int k = 0; k < 32; ++k) wb[k] = wrow[32 + k];
  }
  const float bias = biasv[tid];

  // own-wave h-state init + featL zero-pad (visible after t=0 staging barrier)
  hbuf[wv][u]      = 0.0f;
  hbuf[wv][64 + u] = 0.0f;
  if (tid < 8) featL[2048 + tid] = (float4){0.f, 0.f, 0.f, 0.f};

  const float4* fg = (const float4*)(feat + (size_t)b * TSTEPS * 32);
  float c0 = 0.0f, c1 = 0.0f;

  for (int t = 0; t <= TSTEPS; ++t) {
    // stage feat rows in 256-step halves (block-uniform branch)
    if ((t & 255) == 0 && t < TSTEPS) {
      if (t) __syncthreads();          // all waves done reading previous half
      const float4* src = fg + t * 8;
#pragma unroll
      for (int k = 0; k < 4; ++k) featL[tid + k * 512] = src[tid + k * 512];
      __syncthreads();                 // copy (and pad/h init) visible
    }

    // ---------- gate phase (identical for all waves, all t) ----------
    {
      const float4* vA = (const float4*)&hbuf[wv][0];    // h0[t-1] (own copy)
      const float4* vB = isL1 ? (const float4*)&hbuf[wv][64]   // h1[t-2]
                              : &featL[(t & 255) * 8];         // x_t (padded)
      v2f a0 = {0.f,0.f}, a1 = {0.f,0.f}, a2 = {0.f,0.f}, a3 = {0.f,0.f};
#pragma unroll
      for (int k = 0; k < 16; k += 2) {
        const float4 v0 = vA[k], v1 = vA[k + 1];
        a0 = pkfma(wa[2*k],     (v2f){v0.x, v0.y}, a0);
        a1 = pkfma(wa[2*k + 1], (v2f){v0.z, v0.w}, a1);
        a2 = pkfma(wa[2*k + 2], (v2f){v1.x, v1.y}, a2);
        a3 = pkfma(wa[2*k + 3], (v2f){v1.z, v1.w}, a3);
      }
#pragma unroll
      for (int k = 0; k < 16; k += 2) {
        const float4 v0 = vB[k], v1 = vB[k + 1];
        a0 = pkfma(wb[2*k],     (v2f){v0.x, v0.y}, a0);
        a1 = pkfma(wb[2*k + 1], (v2f){v0.z, v0.w}, a1);
        a2 = pkfma(wb[2*k + 2], (v2f){v1.x, v1.y}, a2);
        a3 = pkfma(wb[2*k + 3], (v2f){v1.z, v1.w}, a3);
      }
      const v2f s = (a0 + a1) + (a2 + a3);
      pre[t & 1][tid] = s.x + s.y + bias;   // boundary-t garbage never consumed
    }

    __syncthreads();   // the ONE barrier: pre[] visible to all waves

    // ---------- update phase ----------
    if (t < TSTEPS) {   // layer0 update (every wave, private copy of h0/c0)
      const float* p = pre[t & 1];
      const float i = sigm(p[u]),        f = sigm(p[64 + u]);
      const float g = tanh_(p[128 + u]), o = sigm(p[192 + u]);
      c0 = fmaf(f, c0, i * g);
      hbuf[wv][u] = o * tanh_(c0);                // h0[t], own slot
    }
    if (isL1 && t >= 1) {   // layer1 update (layer1 waves only)
      const float* p = pre[t & 1] + 256;
      const float i = sigm(p[u]),        f = sigm(p[64 + u]);
      const float g = tanh_(p[128 + u]), o = sigm(p[192 + u]);
      c1 = fmaf(f, c1, i * g);
      hbuf[wv][64 + u] = o * tanh_(c1);           // h1[t-1], own slot
    }
  }

  // fc epilogue: wave 4 wrote h1[T-1] into hbuf[4][64..127]; lanes 0..4 of
  // wave 4 read it (same-wave ordering, no barrier needed)
  if (tid >= 256 && tid < 261) {
    const int j = tid - 256;
    const float* h = &hbuf[4][64];
    float s = fc_b[j];
    const float* wr = fc_w + j * HID;
#pragma unroll
    for (int k = 0; k < HID; ++k) s = fmaf(wr[k], h[k], s);
    out[b * 5 + j] = s;
  }
}

// ---------------------------------------------------------------------------
extern "C" void kernel_launch(void* const* d_in, const int* in_sizes, int n_in,
                              void* d_out, int out_size, void* d_ws, size_t ws_size,
                              hipStream_t stream) {
  (void)in_sizes; (void)n_in; (void)out_size; (void)ws_size;
  const float* x    = (const float*)d_in[0];
  const float* c1w  = (const float*)d_in[1];
  const float* c1b  = (const float*)d_in[2];
  const float* c2w  = (const float*)d_in[3];
  const float* c2b  = (const float*)d_in[4];
  const float* wih0 = (const float*)d_in[5];
  const float* whh0 = (const float*)d_in[6];
  const float* bih0 = (const float*)d_in[7];
  const float* bhh0 = (const float*)d_in[8];
  const float* wih1 = (const float*)d_in[9];
  const float* whh1 = (const float*)d_in[10];
  const float* bih1 = (const float*)d_in[11];
  const float* bhh1 = (const float*)d_in[12];
  const float* fcw  = (const float*)d_in[13];
  const float* fcb  = (const float*)d_in[14];
  float* out = (float*)d_out;

  float* t1    = (float*)d_ws;                      // [256,1024,16] = 16 MB
  float* feat  = t1 + (size_t)256 * 1024 * 16;      // [256,512,32]  = 16 MB
  // Wpack/biasv reuse the t1 region (dead after conv2_pool; stream-ordered)
  float* Wpack = t1;                                // [512][128]
  float* biasv = t1 + 512 * 128;                    // [512]

  conv1_pool<<<1024, 256, 0, stream>>>(x, c1w, c1b, t1);
  conv2_pool<<<512, 256, 0, stream>>>(t1, c2w, c2b, feat);
  pack_weights<<<512, 128, 0, stream>>>(wih0, whh0, bih0, bhh0,
                                        wih1, whh1, bih1, bhh1, Wpack, biasv);
  lstm_fused<<<256, 512, 0, stream>>>(feat, Wpack, biasv, fcw, fcb, out);
}